// Round 4
// baseline (180.518 us; speedup 1.0000x reference)
//
#include <hip/hip_runtime.h>
#include <stdint.h>

// All I/O fp32. MFMA bf16 path, weights as A-operand (A[m=out][k]), activations
// as B (B[k][n=point]). Layer->layer D->B handoff is in-lane only because each
// next layer's weights are pre-permuted along input dim:
//   P(k) = 4*(k>>3) + (k&3) + 16*((k>>2)&1)
// R4: weight frags staged to LDS; two independent 16-point groups (q) for ILP.
// R5 (FAILED): __launch_bounds__(256,4) -> 64 arch VGPR -> massive spill.
// R6: grid 1024, bounds (256,2): identical to R4. Residency capped at
//   2 waves/SIMD by TOTAL unified reg use (~230-256; CSV VGPR_Count is
//   arch-only; R5's forced 128-total budget halved arch regs + spilled).
// R7: native v_cvt_pk_bf16_f32 packs: VALUBusy 27->18%, dur UNCHANGED ->
//   latency-bound, not VALU-bound. Both pipes idle 76% of cycles.
// R8: SPLIT the kernel to break the register peak. pc_mlp (rel->coeffs,
//   biases demoted to transient LDS reads, no bpermute needed) and pc_bank
//   (feat+coeffs->out, 16 indep MFMAs). Coeff handoff: 8 bf16 (16B) per
//   point stashed in out dwords 0-3, overwritten by pc_bank after reading
//   (in-wave program order; numerics identical to the old bf16 cw path).

typedef __attribute__((ext_vector_type(8))) __bf16 bf16x8;
typedef __attribute__((ext_vector_type(2))) __bf16 bf16x2;
typedef __attribute__((ext_vector_type(4))) float f32x4;

union FragU { uint32_t u[4]; bf16x8 v; uint4 q; };

__device__ __forceinline__ unsigned short f2bf(float f) {
    union { float f; uint32_t i; } v; v.f = f;
    return (unsigned short)((v.i + 0x7FFFu + ((v.i >> 16) & 1u)) >> 16); // RTNE (prep only)
}
__device__ __forceinline__ float bf2f(uint32_t u16) {
    union { uint32_t i; float f; } v; v.i = u16 << 16; return v.f;
}
// native pack: compiler lowers cast pairs to v_cvt_pk_bf16_f32 (RTNE)
__device__ __forceinline__ uint32_t pk2(float x, float y) {
    union { bf16x2 h; uint32_t u; } c;
    c.h[0] = (__bf16)x; c.h[1] = (__bf16)y;
    return c.u;
}
__device__ __forceinline__ bf16x8 pack8(float a, float b, float c, float d,
                                        float e, float f, float g, float h) {
    bf16x8 v;
    v[0] = (__bf16)a; v[1] = (__bf16)b; v[2] = (__bf16)c; v[3] = (__bf16)d;
    v[4] = (__bf16)e; v[5] = (__bf16)f; v[6] = (__bf16)g; v[7] = (__bf16)h;
    return v;
}
__device__ __forceinline__ int permK(int k) {
    return 4 * (k >> 3) + (k & 3) + 16 * ((k >> 2) & 1);
}
__device__ __forceinline__ f32x4 MF(bf16x8 a, bf16x8 b, f32x4 c) {
    return __builtin_amdgcn_mfma_f32_16x16x32_bf16(a, b, c, 0, 0, 0);
}

// ws dword layout (10240 dwords):
//   [0,1024)    layer0 A-frags  [chunk(2)][tile(2)][lane(64)][dw(4)]  (K=60 pad 64)
//   [1024,3072) layers1-4 A     [L(4)][tile(2)][lane][dw]             (perm k)
//   [3072,3328) layer5 A        [lane][dw]                            (perm k, m>=8 zero)
//   [3328,7424) bank A          [k(8)][tile(2)][lane][dw]
//   [7424,9984) bias L0-4 fp32  [L(5)][tile(2)][lane][r(4)]
//   [9984,10240) bias L5 fp32   [lane][r]                             (m>=8 zero)

struct WPf { const float* p[13]; };

__global__ void pc_prep(WPf wp, uint32_t* __restrict__ ws) {
    int idx = blockIdx.x * blockDim.x + threadIdx.x;
    if (idx >= 10240) return;
    if (idx < 7424) {
        int layer, t, chunk = 0, lane, d; const float* w; bool perm;
        int r = idx;
        if (r < 1024) { chunk = r >> 9; r &= 511; t = r >> 8; r &= 255; lane = r >> 2; d = r & 3;
                        layer = 0; w = wp.p[0]; perm = false; }
        else if (r < 3072) { r -= 1024; layer = 1 + (r >> 9); r &= 511; t = r >> 8; r &= 255;
                             lane = r >> 2; d = r & 3; w = wp.p[2 * layer]; perm = true; }
        else if (r < 3328) { r -= 3072; layer = 5; t = 0; lane = r >> 2; d = r & 3;
                             w = wp.p[10]; perm = true; }
        else { r -= 3328; int bk = r >> 9; r &= 511; t = r >> 8; r &= 255; lane = r >> 2; d = r & 3;
               layer = -1; w = wp.p[12] + bk * 1024; perm = false; }
        int gq = lane >> 4, m = t * 16 + (lane & 15);
        uint32_t o = 0;
        #pragma unroll
        for (int e = 0; e < 2; ++e) {
            int kf = 8 * gq + 2 * d + e;
            float v = 0.f;
            if (layer == -1) {
                v = w[kf * 32 + m];                       // bank: A[m=o][k=i] = bank[k][i*32+o]
            } else {
                int ks = perm ? permK(kf) : (chunk * 32 + kf);
                if (layer == 0)      { if (ks < 60) v = w[ks * 32 + m]; }
                else if (layer == 5) { if (m < 8)   v = w[ks * 8 + m]; }
                else                 v = w[ks * 32 + m];  // A[m][k] = W[P(k)][m]
            }
            o |= ((uint32_t)f2bf(v)) << (16 * e);
        }
        ws[idx] = o;
    } else if (idx < 9984) {
        int r = idx - 7424; int L = r >> 9; r &= 511; int t = r >> 8; r &= 255;
        int lane = r >> 2, rr = r & 3;
        ((float*)ws)[idx] = wp.p[2 * L + 1][t * 16 + 4 * (lane >> 4) + rr];
    } else {
        int r = idx - 9984; int lane = r >> 2, rr = r & 3;
        int m = 4 * (lane >> 4) + rr;
        ((float*)ws)[idx] = (m < 8) ? wp.p[11][m] : 0.f;
    }
}

#define IT 2   // 32 points/iter * 2 iters = 64 points per wave; 1024 blocks each phase

// ---------------- Phase A: MLP + softmax -> bf16 coeffs in out[dw 0..3] -----
__global__ __launch_bounds__(256) void pc_mlp(
    const float* __restrict__ rel, const uint32_t* __restrict__ wsu,
    uint32_t* __restrict__ outc)
{
    // LDS 24KB: [0,3328) MLP frags (ws[0,3328)), [3328,6144) biases (ws[7424,10240))
    __shared__ __align__(16) uint32_t W[6144];
    {
        uint4* s4 = (uint4*)W;
        const uint4* g4 = (const uint4*)wsu;
        #pragma unroll
        for (int i = 0; i < 6; ++i) {
            int idx = threadIdx.x + 256 * i;            // 0..1535
            s4[idx] = g4[idx < 832 ? idx : idx + 1024]; // frag part / bias part
        }
    }
    __syncthreads();

    const int lane = threadIdx.x & 63;
    const int wv = threadIdx.x >> 6;
    const int g = lane >> 4;
    const int n16 = lane & 15;
    const size_t pt0 = (size_t)(blockIdx.x * 4 + wv) * (32 * IT);

    #define LDF(off) ({ FragU _f; _f.q = ((const uint4*)(W + (off)))[lane]; _f.v; })
    #define LDB(off) ({ float4 _b = ((const float4*)(W + (off)))[lane]; \
                        (f32x4){_b.x, _b.y, _b.z, _b.w}; })

    for (int it = 0; it < IT; ++it) {
        const size_t nA = pt0 + (size_t)it * 32 + n16;   // group 0 point; group 1 = +16

        // ---- layer0 B-frags (K=60, tail pad) for both groups ----
        bf16x8 c0[2], c1[2];
        #pragma unroll
        for (int q = 0; q < 2; ++q) {
            const float* rrow = rel + (nA + 16 * q) * 60;
            float4 ra = *(const float4*)(rrow + 8 * g);
            float4 rb = *(const float4*)(rrow + 8 * g + 4);
            float4 rc = *(const float4*)(rrow + 32 + 8 * g);
            float4 rd = make_float4(0.f, 0.f, 0.f, 0.f);
            if (g < 3) rd = *(const float4*)(rrow + 36 + 8 * g);
            c0[q] = pack8(ra.x, ra.y, ra.z, ra.w, rb.x, rb.y, rb.z, rb.w);
            c1[q] = pack8(rc.x, rc.y, rc.z, rc.w, rd.x, rd.y, rd.z, rd.w);
        }

        f32x4 t0[2], t1[2];
        {
            f32x4 ba = LDB(3328), bb = LDB(3328 + 256);
            bf16x8 w00 = LDF(0), w01 = LDF(256), w10 = LDF(512), w11 = LDF(768);
            #pragma unroll
            for (int q = 0; q < 2; ++q) {
                t0[q] = MF(w00, c0[q], ba); t1[q] = MF(w01, c0[q], bb);
                t0[q] = MF(w10, c1[q], t0[q]); t1[q] = MF(w11, c1[q], t1[q]);
            }
        }

        // ---- layers 1..4: leaky -> in-lane pack -> mfma (perm weights) ----
        #pragma unroll
        for (int L = 0; L < 4; ++L) {
            bf16x8 wa = LDF(1024 + L * 512), wb = LDF(1024 + L * 512 + 256);
            f32x4 ba = LDB(3328 + (L + 1) * 512), bb = LDB(3328 + (L + 1) * 512 + 256);
            #pragma unroll
            for (int q = 0; q < 2; ++q) {
                #pragma unroll
                for (int r = 0; r < 4; ++r) {
                    t0[q][r] = fmaxf(t0[q][r], 0.01f * t0[q][r]);
                    t1[q][r] = fmaxf(t1[q][r], 0.01f * t1[q][r]);
                }
                bf16x8 bx = pack8(t0[q][0], t0[q][1], t0[q][2], t0[q][3],
                                  t1[q][0], t1[q][1], t1[q][2], t1[q][3]);
                t0[q] = MF(wa, bx, ba);
                t1[q] = MF(wb, bx, bb);
            }
        }

        // ---- layer5 (32->8) ----
        {
            bf16x8 w5 = LDF(3072);
            f32x4 b5 = LDB(5888);
            #pragma unroll
            for (int q = 0; q < 2; ++q) {
                #pragma unroll
                for (int r = 0; r < 4; ++r) {
                    t0[q][r] = fmaxf(t0[q][r], 0.01f * t0[q][r]);
                    t1[q][r] = fmaxf(t1[q][r], 0.01f * t1[q][r]);
                }
                bf16x8 bx = pack8(t0[q][0], t0[q][1], t0[q][2], t0[q][3],
                                  t1[q][0], t1[q][1], t1[q][2], t1[q][3]);
                t0[q] = MF(w5, bx, b5);   // logits m0..3 in g=0, m4..7 in g=1
            }
        }

        // ---- softmax over 8 per point; g0 writes c0..3, g1 writes c4..7 ----
        #pragma unroll
        for (int q = 0; q < 2; ++q) {
            float m4 = fmaxf(fmaxf(t0[q][0], t0[q][1]), fmaxf(t0[q][2], t0[q][3]));
            float m8 = fmaxf(m4, __shfl_xor(m4, 16, 64));
            float e0 = __expf(t0[q][0] - m8), e1 = __expf(t0[q][1] - m8);
            float e2 = __expf(t0[q][2] - m8), e3 = __expf(t0[q][3] - m8);
            float s4 = e0 + e1 + e2 + e3;
            float s8 = s4 + __shfl_xor(s4, 16, 64);
            float inv = 1.0f / s8;
            uint32_t p01 = pk2(e0 * inv, e1 * inv);
            uint32_t p23 = pk2(e2 * inv, e3 * inv);
            if (g < 2)
                *(uint2*)(outc + (nA + 16 * q) * 32 + 2 * g) = make_uint2(p01, p23);
        }
    }
    #undef LDF
    #undef LDB
}

// ---------------- Phase B: coeffs + feat -> bank-weighted output ------------
__global__ __launch_bounds__(256) void pc_bank(
    const float* __restrict__ feat, const uint32_t* __restrict__ wsu,
    float* out)
{
    // LDS 16KB: bank frags (ws[3328,7424))
    __shared__ __align__(16) uint32_t W[4096];
    {
        uint4* s4 = (uint4*)W;
        const uint4* g4 = (const uint4*)wsu + 832;   // dword 3328
        #pragma unroll
        for (int i = 0; i < 4; ++i) s4[threadIdx.x + 256 * i] = g4[threadIdx.x + 256 * i];
    }
    __syncthreads();

    const uint32_t* outc = (const uint32_t*)out;
    const int lane = threadIdx.x & 63;
    const int wv = threadIdx.x >> 6;
    const int g = lane >> 4;
    const int n16 = lane & 15;
    const size_t pt0 = (size_t)(blockIdx.x * 4 + wv) * (32 * IT);

    #define LDF(off) ({ FragU _f; _f.q = ((const uint4*)(W + (off)))[lane]; _f.v; })

    for (int it = 0; it < IT; ++it) {
        const size_t nA = pt0 + (size_t)it * 32 + n16;

        // coeffs: 16B per point, same for all 4 g-groups of a point
        uint4 cp[2];
        #pragma unroll
        for (int q = 0; q < 2; ++q)
            cp[q] = *(const uint4*)(outc + (nA + 16 * q) * 32);

        // feat B-frags
        bf16x8 bfr[2];
        #pragma unroll
        for (int q = 0; q < 2; ++q) {
            const float* frow = feat + (nA + 16 * q) * 32 + 8 * g;
            float4 fa = *(const float4*)frow;
            float4 fb = *(const float4*)(frow + 4);
            bfr[q] = pack8(fa.x, fa.y, fa.z, fa.w, fb.x, fb.y, fb.z, fb.w);
        }

        float cw[2][8];
        #pragma unroll
        for (int q = 0; q < 2; ++q) {
            cw[q][0] = bf2f(cp[q].x & 0xffff); cw[q][1] = bf2f(cp[q].x >> 16);
            cw[q][2] = bf2f(cp[q].y & 0xffff); cw[q][3] = bf2f(cp[q].y >> 16);
            cw[q][4] = bf2f(cp[q].z & 0xffff); cw[q][5] = bf2f(cp[q].z >> 16);
            cw[q][6] = bf2f(cp[q].w & 0xffff); cw[q][7] = bf2f(cp[q].w >> 16);
        }

        f32x4 o0[2], o1[2];
        #pragma unroll
        for (int q = 0; q < 2; ++q) {
            o0[q] = (f32x4){0.f, 0.f, 0.f, 0.f};
            o1[q] = (f32x4){0.f, 0.f, 0.f, 0.f};
        }
        #pragma unroll
        for (int k = 0; k < 8; ++k) {
            bf16x8 wk0 = LDF(k * 512), wk1 = LDF(k * 512 + 256);
            #pragma unroll
            for (int q = 0; q < 2; ++q) {
                f32x4 z = {0.f, 0.f, 0.f, 0.f};
                f32x4 u0 = MF(wk0, bfr[q], z);
                f32x4 u1 = MF(wk1, bfr[q], z);
                #pragma unroll
                for (int r = 0; r < 4; ++r) {
                    o0[q][r] += cw[q][k] * u0[r];
                    o1[q][r] += cw[q][k] * u1[r];
                }
            }
        }

        #pragma unroll
        for (int q = 0; q < 2; ++q) {
            float* orow = out + (nA + 16 * q) * 32;
            *(float4*)(orow + 4 * g)      = make_float4(o0[q][0], o0[q][1], o0[q][2], o0[q][3]);
            *(float4*)(orow + 16 + 4 * g) = make_float4(o1[q][0], o1[q][1], o1[q][2], o1[q][3]);
        }
    }
    #undef LDF
}

extern "C" void kernel_launch(void* const* d_in, const int* in_sizes, int n_in,
                              void* d_out, int out_size, void* d_ws, size_t ws_size,
                              hipStream_t stream)
{
    const float* rel = (const float*)d_in[0];
    const float* feat = (const float*)d_in[1];
    WPf wp;
    for (int i = 0; i < 13; ++i) wp.p[i] = (const float*)d_in[2 + i];
    uint32_t* ws = (uint32_t*)d_ws;
    float* out = (float*)d_out;

    const int npts = in_sizes[0] / 60;                 // 262144
    const int nblocks = npts / (32 * IT * 4);          // 1024

    hipLaunchKernelGGL(pc_prep, dim3(40), dim3(256), 0, stream, wp, ws);
    hipLaunchKernelGGL(pc_mlp, dim3(nblocks), dim3(256), 0, stream, rel, ws, (uint32_t*)out);
    hipLaunchKernelGGL(pc_bank, dim3(nblocks), dim3(256), 0, stream, feat, ws, out);
}

// Round 5
// 161.475 us; speedup vs baseline: 1.1179x; 1.1179x over previous
//
#include <hip/hip_runtime.h>
#include <stdint.h>

// All I/O fp32. MFMA bf16 path, weights as A-operand (A[m=out][k]), activations
// as B (B[k][n=point]). Layer->layer D->B handoff is in-lane only because each
// next layer's weights are pre-permuted along input dim:
//   P(k) = 4*(k>>3) + (k&3) + 16*((k>>2)&1)
// R4: weight frags staged to LDS; two independent 16-point groups (q) for ILP.
// R5 (FAILED): __launch_bounds__(256,4) -> 64 arch VGPR -> massive spill.
// R6: grid 1024: dur identical to R4 -> residency capped at 2 waves/SIMD by
//   TOTAL unified reg use (~256; CSV VGPR_Count is arch-only).
// R7: native cvt_pk packs: VALUBusy 27->18%, dur unchanged -> latency-bound.
// R8 (FAILED): two-kernel split; coeff handoff through out = partial-line
//   HBM round-trip (+~100MB effective traffic) + extra launch: 63us vs 41.
// R9: split INSIDE the wave. Phase 1 (MLP+softmax, biases as transient LDS
//   reads, all IT iters) parks 16B/point coeffs in a per-wave LDS strip (no
//   barrier, no bpermute); phase 2 (bank stage) reads them back. Register
//   liveness = max(phase1, phase2) ~= 90-120, not the union (~256).
//   LDS 44KB -> 3 blocks/CU; __launch_bounds__(256,3) -> ~170-reg budget.
//   Spill tripwire: WRITE_SIZE >> 33MB means budget too tight -> revert.

typedef __attribute__((ext_vector_type(8))) __bf16 bf16x8;
typedef __attribute__((ext_vector_type(2))) __bf16 bf16x2;
typedef __attribute__((ext_vector_type(4))) float f32x4;

union FragU { uint32_t u[4]; bf16x8 v; uint4 q; };

__device__ __forceinline__ unsigned short f2bf(float f) {
    union { float f; uint32_t i; } v; v.f = f;
    return (unsigned short)((v.i + 0x7FFFu + ((v.i >> 16) & 1u)) >> 16); // RTNE (prep only)
}
__device__ __forceinline__ float bf2f(uint32_t u16) {
    union { uint32_t i; float f; } v; v.i = u16 << 16; return v.f;
}
// native pack: compiler lowers cast pairs to v_cvt_pk_bf16_f32 (RTNE)
__device__ __forceinline__ uint32_t pk2(float x, float y) {
    union { bf16x2 h; uint32_t u; } c;
    c.h[0] = (__bf16)x; c.h[1] = (__bf16)y;
    return c.u;
}
__device__ __forceinline__ bf16x8 pack8(float a, float b, float c, float d,
                                        float e, float f, float g, float h) {
    bf16x8 v;
    v[0] = (__bf16)a; v[1] = (__bf16)b; v[2] = (__bf16)c; v[3] = (__bf16)d;
    v[4] = (__bf16)e; v[5] = (__bf16)f; v[6] = (__bf16)g; v[7] = (__bf16)h;
    return v;
}
__device__ __forceinline__ int permK(int k) {
    return 4 * (k >> 3) + (k & 3) + 16 * ((k >> 2) & 1);
}
__device__ __forceinline__ f32x4 MF(bf16x8 a, bf16x8 b, f32x4 c) {
    return __builtin_amdgcn_mfma_f32_16x16x32_bf16(a, b, c, 0, 0, 0);
}

// ws dword layout (10240 dwords):
//   [0,1024)    layer0 A-frags  [chunk(2)][tile(2)][lane(64)][dw(4)]  (K=60 pad 64)
//   [1024,3072) layers1-4 A     [L(4)][tile(2)][lane][dw]             (perm k)
//   [3072,3328) layer5 A        [lane][dw]                            (perm k, m>=8 zero)
//   [3328,7424) bank A          [k(8)][tile(2)][lane][dw]
//   [7424,9984) bias L0-4 fp32  [L(5)][tile(2)][lane][r(4)]
//   [9984,10240) bias L5 fp32   [lane][r]                             (m>=8 zero)

struct WPf { const float* p[13]; };

__global__ void pc_prep(WPf wp, uint32_t* __restrict__ ws) {
    int idx = blockIdx.x * blockDim.x + threadIdx.x;
    if (idx >= 10240) return;
    if (idx < 7424) {
        int layer, t, chunk = 0, lane, d; const float* w; bool perm;
        int r = idx;
        if (r < 1024) { chunk = r >> 9; r &= 511; t = r >> 8; r &= 255; lane = r >> 2; d = r & 3;
                        layer = 0; w = wp.p[0]; perm = false; }
        else if (r < 3072) { r -= 1024; layer = 1 + (r >> 9); r &= 511; t = r >> 8; r &= 255;
                             lane = r >> 2; d = r & 3; w = wp.p[2 * layer]; perm = true; }
        else if (r < 3328) { r -= 3072; layer = 5; t = 0; lane = r >> 2; d = r & 3;
                             w = wp.p[10]; perm = true; }
        else { r -= 3328; int bk = r >> 9; r &= 511; t = r >> 8; r &= 255; lane = r >> 2; d = r & 3;
               layer = -1; w = wp.p[12] + bk * 1024; perm = false; }
        int gq = lane >> 4, m = t * 16 + (lane & 15);
        uint32_t o = 0;
        #pragma unroll
        for (int e = 0; e < 2; ++e) {
            int kf = 8 * gq + 2 * d + e;
            float v = 0.f;
            if (layer == -1) {
                v = w[kf * 32 + m];                       // bank: A[m=o][k=i] = bank[k][i*32+o]
            } else {
                int ks = perm ? permK(kf) : (chunk * 32 + kf);
                if (layer == 0)      { if (ks < 60) v = w[ks * 32 + m]; }
                else if (layer == 5) { if (m < 8)   v = w[ks * 8 + m]; }
                else                 v = w[ks * 32 + m];  // A[m][k] = W[P(k)][m]
            }
            o |= ((uint32_t)f2bf(v)) << (16 * e);
        }
        ws[idx] = o;
    } else if (idx < 9984) {
        int r = idx - 7424; int L = r >> 9; r &= 511; int t = r >> 8; r &= 255;
        int lane = r >> 2, rr = r & 3;
        ((float*)ws)[idx] = wp.p[2 * L + 1][t * 16 + 4 * (lane >> 4) + rr];
    } else {
        int r = idx - 9984; int lane = r >> 2, rr = r & 3;
        int m = 4 * (lane >> 4) + rr;
        ((float*)ws)[idx] = (m < 8) ? wp.p[11][m] : 0.f;
    }
}

#define IT 2   // 32 points/iter * 2 iters = 64 points per wave; 1024 blocks

// W LDS dword map (11264 dwords = 44KB):
//   [0,3328)      MLP frags       (ws [0,3328))
//   [3328,6144)   biases fp32     (ws [7424,10240))
//   [6144,10240)  bank frags      (ws [3328,7424))
//   [10240,11264) coeffs: 4 dw/point, per-wave private strip (256 points/block)
#define CO 10240

__global__ __launch_bounds__(256, 3) void pc_main(
    const float* __restrict__ rel, const float* __restrict__ feat,
    const uint32_t* __restrict__ wsu, float* __restrict__ out)
{
    __shared__ __align__(16) uint32_t W[11264];
    { // cooperative stage of all frags/biases: 2560 x uint4, remapped
        uint4* s4 = (uint4*)W;
        const uint4* g4 = (const uint4*)wsu;
        #pragma unroll
        for (int i = 0; i < 10; ++i) {
            int idx = threadIdx.x + 256 * i;             // 0..2559 (uint4 units)
            int src = (idx < 832) ? idx                  // MLP frags
                    : (idx < 1536) ? idx + 1024          // biases (ws dw 7424+)
                    : idx - 704;                         // bank   (ws dw 3328+)
            s4[idx] = g4[src];
        }
    }
    __syncthreads();

    const int lane = threadIdx.x & 63;
    const int wv = threadIdx.x >> 6;
    const int g = lane >> 4;
    const int n16 = lane & 15;
    const size_t pt0 = (size_t)(blockIdx.x * 4 + wv) * (32 * IT);
    const int pbase = wv * (32 * IT);                    // point index within block

    #define LDF(off) ({ FragU _f; _f.q = ((const uint4*)(W + (off)))[lane]; _f.v; })
    #define LDB(off) ({ float4 _b = ((const float4*)(W + (off)))[lane]; \
                        (f32x4){_b.x, _b.y, _b.z, _b.w}; })

    // ================= Phase 1: MLP + softmax -> coeffs in LDS ==============
    for (int it = 0; it < IT; ++it) {
        const size_t nA = pt0 + (size_t)it * 32 + n16;   // group 0 point; group 1 = +16

        // ---- layer0 B-frags (K=60, tail pad) for both groups ----
        bf16x8 c0[2], c1[2];
        #pragma unroll
        for (int q = 0; q < 2; ++q) {
            const float* rrow = rel + (nA + 16 * q) * 60;
            float4 ra = *(const float4*)(rrow + 8 * g);
            float4 rb = *(const float4*)(rrow + 8 * g + 4);
            float4 rc = *(const float4*)(rrow + 32 + 8 * g);
            float4 rd = make_float4(0.f, 0.f, 0.f, 0.f);
            if (g < 3) rd = *(const float4*)(rrow + 36 + 8 * g);
            c0[q] = pack8(ra.x, ra.y, ra.z, ra.w, rb.x, rb.y, rb.z, rb.w);
            c1[q] = pack8(rc.x, rc.y, rc.z, rc.w, rd.x, rd.y, rd.z, rd.w);
        }

        f32x4 t0[2], t1[2];
        {
            f32x4 ba = LDB(3328), bb = LDB(3328 + 256);
            bf16x8 w00 = LDF(0), w01 = LDF(256), w10 = LDF(512), w11 = LDF(768);
            #pragma unroll
            for (int q = 0; q < 2; ++q) {
                t0[q] = MF(w00, c0[q], ba);    t1[q] = MF(w01, c0[q], bb);
                t0[q] = MF(w10, c1[q], t0[q]); t1[q] = MF(w11, c1[q], t1[q]);
            }
        }

        // ---- layers 1..4: leaky -> in-lane pack -> mfma (perm weights) ----
        #pragma unroll
        for (int L = 0; L < 4; ++L) {
            bf16x8 wa = LDF(1024 + L * 512), wb = LDF(1024 + L * 512 + 256);
            f32x4 ba = LDB(3328 + (L + 1) * 512), bb = LDB(3328 + (L + 1) * 512 + 256);
            #pragma unroll
            for (int q = 0; q < 2; ++q) {
                #pragma unroll
                for (int r = 0; r < 4; ++r) {
                    t0[q][r] = fmaxf(t0[q][r], 0.01f * t0[q][r]);
                    t1[q][r] = fmaxf(t1[q][r], 0.01f * t1[q][r]);
                }
                bf16x8 bx = pack8(t0[q][0], t0[q][1], t0[q][2], t0[q][3],
                                  t1[q][0], t1[q][1], t1[q][2], t1[q][3]);
                t0[q] = MF(wa, bx, ba);
                t1[q] = MF(wb, bx, bb);
            }
        }

        // ---- layer5 (32->8) ----
        {
            bf16x8 w5 = LDF(3072);
            f32x4 b5 = LDB(5888);
            #pragma unroll
            for (int q = 0; q < 2; ++q) {
                #pragma unroll
                for (int r = 0; r < 4; ++r) {
                    t0[q][r] = fmaxf(t0[q][r], 0.01f * t0[q][r]);
                    t1[q][r] = fmaxf(t1[q][r], 0.01f * t1[q][r]);
                }
                bf16x8 bx = pack8(t0[q][0], t0[q][1], t0[q][2], t0[q][3],
                                  t1[q][0], t1[q][1], t1[q][2], t1[q][3]);
                t0[q] = MF(w5, bx, b5);   // logits m0..3 in g=0, m4..7 in g=1
            }
        }

        // ---- softmax over 8 per point; g0 parks c0..3, g1 parks c4..7 ----
        #pragma unroll
        for (int q = 0; q < 2; ++q) {
            float m4 = fmaxf(fmaxf(t0[q][0], t0[q][1]), fmaxf(t0[q][2], t0[q][3]));
            float m8 = fmaxf(m4, __shfl_xor(m4, 16, 64));
            float e0 = __expf(t0[q][0] - m8), e1 = __expf(t0[q][1] - m8);
            float e2 = __expf(t0[q][2] - m8), e3 = __expf(t0[q][3] - m8);
            float s4 = e0 + e1 + e2 + e3;
            float s8 = s4 + __shfl_xor(s4, 16, 64);
            float inv = 1.0f / s8;
            uint32_t p01 = pk2(e0 * inv, e1 * inv);
            uint32_t p23 = pk2(e2 * inv, e3 * inv);
            if (g < 2) {
                int p = pbase + it * 32 + q * 16 + n16;
                *(uint2*)(W + CO + p * 4 + 2 * g) = make_uint2(p01, p23);
            }
        }
    }

    // ================= Phase 2: bank stage (coeffs from LDS) ================
    for (int it = 0; it < IT; ++it) {
        const size_t nA = pt0 + (size_t)it * 32 + n16;
        const int p0 = pbase + it * 32 + n16;

        // coeffs: 16B per point, broadcast to all 4 g-groups via LDS read
        uint4 cp[2];
        #pragma unroll
        for (int q = 0; q < 2; ++q)
            cp[q] = *(const uint4*)(W + CO + (p0 + 16 * q) * 4);

        // feat B-frags
        bf16x8 bfr[2];
        #pragma unroll
        for (int q = 0; q < 2; ++q) {
            const float* frow = feat + (nA + 16 * q) * 32 + 8 * g;
            float4 fa = *(const float4*)frow;
            float4 fb = *(const float4*)(frow + 4);
            bfr[q] = pack8(fa.x, fa.y, fa.z, fa.w, fb.x, fb.y, fb.z, fb.w);
        }

        float cw[2][8];
        #pragma unroll
        for (int q = 0; q < 2; ++q) {
            cw[q][0] = bf2f(cp[q].x & 0xffff); cw[q][1] = bf2f(cp[q].x >> 16);
            cw[q][2] = bf2f(cp[q].y & 0xffff); cw[q][3] = bf2f(cp[q].y >> 16);
            cw[q][4] = bf2f(cp[q].z & 0xffff); cw[q][5] = bf2f(cp[q].z >> 16);
            cw[q][6] = bf2f(cp[q].w & 0xffff); cw[q][7] = bf2f(cp[q].w >> 16);
        }

        f32x4 o0[2], o1[2];
        #pragma unroll
        for (int q = 0; q < 2; ++q) {
            o0[q] = (f32x4){0.f, 0.f, 0.f, 0.f};
            o1[q] = (f32x4){0.f, 0.f, 0.f, 0.f};
        }
        #pragma unroll
        for (int k = 0; k < 8; ++k) {
            bf16x8 wk0 = LDF(6144 + k * 512), wk1 = LDF(6144 + k * 512 + 256);
            #pragma unroll
            for (int q = 0; q < 2; ++q) {
                f32x4 z = {0.f, 0.f, 0.f, 0.f};
                f32x4 u0 = MF(wk0, bfr[q], z);
                f32x4 u1 = MF(wk1, bfr[q], z);
                #pragma unroll
                for (int r = 0; r < 4; ++r) {
                    o0[q][r] += cw[q][k] * u0[r];
                    o1[q][r] += cw[q][k] * u1[r];
                }
            }
        }

        #pragma unroll
        for (int q = 0; q < 2; ++q) {
            float* orow = out + (nA + 16 * q) * 32;
            *(float4*)(orow + 4 * g)      = make_float4(o0[q][0], o0[q][1], o0[q][2], o0[q][3]);
            *(float4*)(orow + 16 + 4 * g) = make_float4(o1[q][0], o1[q][1], o1[q][2], o1[q][3]);
        }
    }
    #undef LDF
    #undef LDB
}

extern "C" void kernel_launch(void* const* d_in, const int* in_sizes, int n_in,
                              void* d_out, int out_size, void* d_ws, size_t ws_size,
                              hipStream_t stream)
{
    const float* rel = (const float*)d_in[0];
    const float* feat = (const float*)d_in[1];
    WPf wp;
    for (int i = 0; i < 13; ++i) wp.p[i] = (const float*)d_in[2 + i];
    uint32_t* ws = (uint32_t*)d_ws;
    float* out = (float*)d_out;

    const int npts = in_sizes[0] / 60;                 // 262144
    const int nblocks = npts / (32 * IT * 4);          // 1024

    hipLaunchKernelGGL(pc_prep, dim3(40), dim3(256), 0, stream, wp, ws);
    hipLaunchKernelGGL(pc_main, dim3(nblocks), dim3(256), 0, stream, rel, feat, ws, out);
}

// Round 6
// 160.477 us; speedup vs baseline: 1.1249x; 1.0062x over previous
//
#include <hip/hip_runtime.h>
#include <stdint.h>

// All I/O fp32. MFMA bf16 path, weights as A-operand (A[m=out][k]), activations
// as B (B[k][n=point]). Layer->layer D->B handoff is in-lane only because each
// next layer's weights are pre-permuted along input dim:
//   P(k) = 4*(k>>3) + (k&3) + 16*((k>>2)&1)
// R4: weight frags staged to LDS; two independent 16-point groups (q) for ILP.
// R5 (FAILED): __launch_bounds__(256,4) -> 64 arch VGPR -> massive spill.
// R6: grid 1024: dur identical to R4 -> residency capped by TOTAL unified regs.
// R7: native cvt_pk packs: VALUBusy 27->18%, dur unchanged -> latency-bound.
// R8 (FAILED): two-kernel split; coeff handoff through out = HBM round-trip.
// R9: in-wave phase split, biases->LDS: VGPR 84, no spill, Occ 20.4% -- dur
//   STILL 42us. Diagnosis: LDS 44KB -> 3 blocks/CU resident but grid gives
//   4 work-blocks/CU -> batches of 3 then 1 -> avg 2 blocks/CU, same as R6/R7.
//   The residency gain was eaten by the work/residency tail.
// R10: (a) IT=1, grid 2048 = 8 work-blocks/CU -> batches 3/3/2, avg 2.67,
//   tail cost 50%->8%. Coeff strip 2KB -> LDS 42KB keeps 3 blocks/CU.
//   (b) hoist rel+feat global loads above the LDS staging loop: feat's
//   ~900cy HBM-cold latency hides under the whole phase-1 MLP; rel's hides
//   under staging. One latency exposure per wave instead of two.
//   Spill tripwire: WRITE_SIZE >> 33MB -> feat hoist overshot, revert.

typedef __attribute__((ext_vector_type(8))) __bf16 bf16x8;
typedef __attribute__((ext_vector_type(2))) __bf16 bf16x2;
typedef __attribute__((ext_vector_type(4))) float f32x4;

union FragU { uint32_t u[4]; bf16x8 v; uint4 q; };

__device__ __forceinline__ unsigned short f2bf(float f) {
    union { float f; uint32_t i; } v; v.f = f;
    return (unsigned short)((v.i + 0x7FFFu + ((v.i >> 16) & 1u)) >> 16); // RTNE (prep only)
}
__device__ __forceinline__ float bf2f(uint32_t u16) {
    union { uint32_t i; float f; } v; v.i = u16 << 16; return v.f;
}
// native pack: compiler lowers cast pairs to v_cvt_pk_bf16_f32 (RTNE)
__device__ __forceinline__ uint32_t pk2(float x, float y) {
    union { bf16x2 h; uint32_t u; } c;
    c.h[0] = (__bf16)x; c.h[1] = (__bf16)y;
    return c.u;
}
__device__ __forceinline__ bf16x8 pack8(float a, float b, float c, float d,
                                        float e, float f, float g, float h) {
    bf16x8 v;
    v[0] = (__bf16)a; v[1] = (__bf16)b; v[2] = (__bf16)c; v[3] = (__bf16)d;
    v[4] = (__bf16)e; v[5] = (__bf16)f; v[6] = (__bf16)g; v[7] = (__bf16)h;
    return v;
}
__device__ __forceinline__ int permK(int k) {
    return 4 * (k >> 3) + (k & 3) + 16 * ((k >> 2) & 1);
}
__device__ __forceinline__ f32x4 MF(bf16x8 a, bf16x8 b, f32x4 c) {
    return __builtin_amdgcn_mfma_f32_16x16x32_bf16(a, b, c, 0, 0, 0);
}

// ws dword layout (10240 dwords):
//   [0,1024)    layer0 A-frags  [chunk(2)][tile(2)][lane(64)][dw(4)]  (K=60 pad 64)
//   [1024,3072) layers1-4 A     [L(4)][tile(2)][lane][dw]             (perm k)
//   [3072,3328) layer5 A        [lane][dw]                            (perm k, m>=8 zero)
//   [3328,7424) bank A          [k(8)][tile(2)][lane][dw]
//   [7424,9984) bias L0-4 fp32  [L(5)][tile(2)][lane][r(4)]
//   [9984,10240) bias L5 fp32   [lane][r]                             (m>=8 zero)

struct WPf { const float* p[13]; };

__global__ void pc_prep(WPf wp, uint32_t* __restrict__ ws) {
    int idx = blockIdx.x * blockDim.x + threadIdx.x;
    if (idx >= 10240) return;
    if (idx < 7424) {
        int layer, t, chunk = 0, lane, d; const float* w; bool perm;
        int r = idx;
        if (r < 1024) { chunk = r >> 9; r &= 511; t = r >> 8; r &= 255; lane = r >> 2; d = r & 3;
                        layer = 0; w = wp.p[0]; perm = false; }
        else if (r < 3072) { r -= 1024; layer = 1 + (r >> 9); r &= 511; t = r >> 8; r &= 255;
                             lane = r >> 2; d = r & 3; w = wp.p[2 * layer]; perm = true; }
        else if (r < 3328) { r -= 3072; layer = 5; t = 0; lane = r >> 2; d = r & 3;
                             w = wp.p[10]; perm = true; }
        else { r -= 3328; int bk = r >> 9; r &= 511; t = r >> 8; r &= 255; lane = r >> 2; d = r & 3;
               layer = -1; w = wp.p[12] + bk * 1024; perm = false; }
        int gq = lane >> 4, m = t * 16 + (lane & 15);
        uint32_t o = 0;
        #pragma unroll
        for (int e = 0; e < 2; ++e) {
            int kf = 8 * gq + 2 * d + e;
            float v = 0.f;
            if (layer == -1) {
                v = w[kf * 32 + m];                       // bank: A[m=o][k=i] = bank[k][i*32+o]
            } else {
                int ks = perm ? permK(kf) : (chunk * 32 + kf);
                if (layer == 0)      { if (ks < 60) v = w[ks * 32 + m]; }
                else if (layer == 5) { if (m < 8)   v = w[ks * 8 + m]; }
                else                 v = w[ks * 32 + m];  // A[m][k] = W[P(k)][m]
            }
            o |= ((uint32_t)f2bf(v)) << (16 * e);
        }
        ws[idx] = o;
    } else if (idx < 9984) {
        int r = idx - 7424; int L = r >> 9; r &= 511; int t = r >> 8; r &= 255;
        int lane = r >> 2, rr = r & 3;
        ((float*)ws)[idx] = wp.p[2 * L + 1][t * 16 + 4 * (lane >> 4) + rr];
    } else {
        int r = idx - 9984; int lane = r >> 2, rr = r & 3;
        int m = 4 * (lane >> 4) + rr;
        ((float*)ws)[idx] = (m < 8) ? wp.p[11][m] : 0.f;
    }
}

// 32 points per wave (2 groups x 16), 4 waves/block = 128 points/block

// W LDS dword map (10752 dwords = 42KB):
//   [0,3328)      MLP frags       (ws [0,3328))
//   [3328,6144)   biases fp32     (ws [7424,10240))
//   [6144,10240)  bank frags      (ws [3328,7424))
//   [10240,10752) coeffs: 4 dw/point, per-wave private strip (128 points/block)
#define CO 10240

__global__ __launch_bounds__(256, 3) void pc_main(
    const float* __restrict__ rel, const float* __restrict__ feat,
    const uint32_t* __restrict__ wsu, float* __restrict__ out)
{
    __shared__ __align__(16) uint32_t W[10752];

    const int lane = threadIdx.x & 63;
    const int wv = threadIdx.x >> 6;
    const int g = lane >> 4;
    const int n16 = lane & 15;
    const size_t nA = (size_t)blockIdx.x * 128 + wv * 32 + n16;   // group 0; group 1 = +16

    // ---- EARLY global loads: rel (needed in phase 1) + feat (phase 2) ----
    // Issued before LDS staging so HBM latency overlaps staging + MLP chain.
    float4 ra[2], rb[2], rc[2], rd[2], fa[2], fb[2];
    #pragma unroll
    for (int q = 0; q < 2; ++q) {
        const float* rrow = rel + (nA + 16 * q) * 60;
        ra[q] = *(const float4*)(rrow + 8 * g);
        rb[q] = *(const float4*)(rrow + 8 * g + 4);
        rc[q] = *(const float4*)(rrow + 32 + 8 * g);
        rd[q] = make_float4(0.f, 0.f, 0.f, 0.f);
        if (g < 3) rd[q] = *(const float4*)(rrow + 36 + 8 * g);
        const float* frow = feat + (nA + 16 * q) * 32 + 8 * g;
        fa[q] = *(const float4*)frow;
        fb[q] = *(const float4*)(frow + 4);
    }

    { // cooperative stage of all frags/biases: 2560 x uint4, remapped
        uint4* s4 = (uint4*)W;
        const uint4* g4 = (const uint4*)wsu;
        #pragma unroll
        for (int i = 0; i < 10; ++i) {
            int idx = threadIdx.x + 256 * i;             // 0..2559 (uint4 units)
            int src = (idx < 832) ? idx                  // MLP frags
                    : (idx < 1536) ? idx + 1024          // biases (ws dw 7424+)
                    : idx - 704;                         // bank   (ws dw 3328+)
            s4[idx] = g4[src];
        }
    }
    __syncthreads();

    #define LDF(off) ({ FragU _f; _f.q = ((const uint4*)(W + (off)))[lane]; _f.v; })
    #define LDB(off) ({ float4 _b = ((const float4*)(W + (off)))[lane]; \
                        (f32x4){_b.x, _b.y, _b.z, _b.w}; })

    // ================= Phase 1: MLP + softmax -> coeffs in LDS ==============
    {
        bf16x8 c0[2], c1[2];
        #pragma unroll
        for (int q = 0; q < 2; ++q) {
            c0[q] = pack8(ra[q].x, ra[q].y, ra[q].z, ra[q].w,
                          rb[q].x, rb[q].y, rb[q].z, rb[q].w);
            c1[q] = pack8(rc[q].x, rc[q].y, rc[q].z, rc[q].w,
                          rd[q].x, rd[q].y, rd[q].z, rd[q].w);
        }

        f32x4 t0[2], t1[2];
        {
            f32x4 ba = LDB(3328), bb = LDB(3328 + 256);
            bf16x8 w00 = LDF(0), w01 = LDF(256), w10 = LDF(512), w11 = LDF(768);
            #pragma unroll
            for (int q = 0; q < 2; ++q) {
                t0[q] = MF(w00, c0[q], ba);    t1[q] = MF(w01, c0[q], bb);
                t0[q] = MF(w10, c1[q], t0[q]); t1[q] = MF(w11, c1[q], t1[q]);
            }
        }

        // ---- layers 1..4: leaky -> in-lane pack -> mfma (perm weights) ----
        #pragma unroll
        for (int L = 0; L < 4; ++L) {
            bf16x8 wa = LDF(1024 + L * 512), wb = LDF(1024 + L * 512 + 256);
            f32x4 ba = LDB(3328 + (L + 1) * 512), bb = LDB(3328 + (L + 1) * 512 + 256);
            #pragma unroll
            for (int q = 0; q < 2; ++q) {
                #pragma unroll
                for (int r = 0; r < 4; ++r) {
                    t0[q][r] = fmaxf(t0[q][r], 0.01f * t0[q][r]);
                    t1[q][r] = fmaxf(t1[q][r], 0.01f * t1[q][r]);
                }
                bf16x8 bx = pack8(t0[q][0], t0[q][1], t0[q][2], t0[q][3],
                                  t1[q][0], t1[q][1], t1[q][2], t1[q][3]);
                t0[q] = MF(wa, bx, ba);
                t1[q] = MF(wb, bx, bb);
            }
        }

        // ---- layer5 (32->8) ----
        {
            bf16x8 w5 = LDF(3072);
            f32x4 b5 = LDB(5888);
            #pragma unroll
            for (int q = 0; q < 2; ++q) {
                #pragma unroll
                for (int r = 0; r < 4; ++r) {
                    t0[q][r] = fmaxf(t0[q][r], 0.01f * t0[q][r]);
                    t1[q][r] = fmaxf(t1[q][r], 0.01f * t1[q][r]);
                }
                bf16x8 bx = pack8(t0[q][0], t0[q][1], t0[q][2], t0[q][3],
                                  t1[q][0], t1[q][1], t1[q][2], t1[q][3]);
                t0[q] = MF(w5, bx, b5);   // logits m0..3 in g=0, m4..7 in g=1
            }
        }

        // ---- softmax over 8 per point; g0 parks c0..3, g1 parks c4..7 ----
        #pragma unroll
        for (int q = 0; q < 2; ++q) {
            float m4 = fmaxf(fmaxf(t0[q][0], t0[q][1]), fmaxf(t0[q][2], t0[q][3]));
            float m8 = fmaxf(m4, __shfl_xor(m4, 16, 64));
            float e0 = __expf(t0[q][0] - m8), e1 = __expf(t0[q][1] - m8);
            float e2 = __expf(t0[q][2] - m8), e3 = __expf(t0[q][3] - m8);
            float s4 = e0 + e1 + e2 + e3;
            float s8 = s4 + __shfl_xor(s4, 16, 64);
            float inv = 1.0f / s8;
            uint32_t p01 = pk2(e0 * inv, e1 * inv);
            uint32_t p23 = pk2(e2 * inv, e3 * inv);
            if (g < 2) {
                int p = wv * 32 + q * 16 + n16;
                *(uint2*)(W + CO + p * 4 + 2 * g) = make_uint2(p01, p23);
            }
        }
    }

    // ================= Phase 2: bank stage (coeffs from LDS) ================
    {
        // coeffs: 16B per point, broadcast to all 4 g-groups via LDS read
        uint4 cp[2];
        #pragma unroll
        for (int q = 0; q < 2; ++q)
            cp[q] = *(const uint4*)(W + CO + (wv * 32 + q * 16 + n16) * 4);

        // feat B-frags from the preloaded float4s
        bf16x8 bfr[2];
        #pragma unroll
        for (int q = 0; q < 2; ++q)
            bfr[q] = pack8(fa[q].x, fa[q].y, fa[q].z, fa[q].w,
                           fb[q].x, fb[q].y, fb[q].z, fb[q].w);

        float cw[2][8];
        #pragma unroll
        for (int q = 0; q < 2; ++q) {
            cw[q][0] = bf2f(cp[q].x & 0xffff); cw[q][1] = bf2f(cp[q].x >> 16);
            cw[q][2] = bf2f(cp[q].y & 0xffff); cw[q][3] = bf2f(cp[q].y >> 16);
            cw[q][4] = bf2f(cp[q].z & 0xffff); cw[q][5] = bf2f(cp[q].z >> 16);
            cw[q][6] = bf2f(cp[q].w & 0xffff); cw[q][7] = bf2f(cp[q].w >> 16);
        }

        f32x4 o0[2], o1[2];
        #pragma unroll
        for (int q = 0; q < 2; ++q) {
            o0[q] = (f32x4){0.f, 0.f, 0.f, 0.f};
            o1[q] = (f32x4){0.f, 0.f, 0.f, 0.f};
        }
        #pragma unroll
        for (int k = 0; k < 8; ++k) {
            bf16x8 wk0 = LDF(6144 + k * 512), wk1 = LDF(6144 + k * 512 + 256);
            #pragma unroll
            for (int q = 0; q < 2; ++q) {
                f32x4 z = {0.f, 0.f, 0.f, 0.f};
                f32x4 u0 = MF(wk0, bfr[q], z);
                f32x4 u1 = MF(wk1, bfr[q], z);
                #pragma unroll
                for (int r = 0; r < 4; ++r) {
                    o0[q][r] += cw[q][k] * u0[r];
                    o1[q][r] += cw[q][k] * u1[r];
                }
            }
        }

        #pragma unroll
        for (int q = 0; q < 2; ++q) {
            float* orow = out + (nA + 16 * q) * 32;
            *(float4*)(orow + 4 * g)      = make_float4(o0[q][0], o0[q][1], o0[q][2], o0[q][3]);
            *(float4*)(orow + 16 + 4 * g) = make_float4(o1[q][0], o1[q][1], o1[q][2], o1[q][3]);
        }
    }
    #undef LDF
    #undef LDB
}

extern "C" void kernel_launch(void* const* d_in, const int* in_sizes, int n_in,
                              void* d_out, int out_size, void* d_ws, size_t ws_size,
                              hipStream_t stream)
{
    const float* rel = (const float*)d_in[0];
    const float* feat = (const float*)d_in[1];
    WPf wp;
    for (int i = 0; i < 13; ++i) wp.p[i] = (const float*)d_in[2 + i];
    uint32_t* ws = (uint32_t*)d_ws;
    float* out = (float*)d_out;

    const int npts = in_sizes[0] / 60;                 // 262144
    const int nblocks = npts / 128;                    // 2048 -> 8 work-blocks/CU

    hipLaunchKernelGGL(pc_prep, dim3(40), dim3(256), 0, stream, wp, ws);
    hipLaunchKernelGGL(pc_main, dim3(nblocks), dim3(256), 0, stream, rel, feat, ws, out);
}